// Round 18
// baseline (137.827 us; speedup 1.0000x reference)
//
#include <hip/hip_runtime.h>
#include <math.h>

#define NB    2
#define NQ    900
#define NQP   960
#define NKV   4096
#define DIMM  256
#define NHEAD 8
#define HD    32
#define RPEH  512
#define GRID  64
#define SPLIT 4

#define LOG2E 1.4426950408889634f

typedef short short8 __attribute__((ext_vector_type(8)));
typedef float f32x4 __attribute__((ext_vector_type(4)));
typedef unsigned uint2v __attribute__((ext_vector_type(2)));
typedef unsigned short u16;
typedef unsigned short u16x4 __attribute__((ext_vector_type(4)));

__device__ inline u16 f2bf(float f) {
    unsigned u = __builtin_bit_cast(unsigned, f);
    u += 0x7fff + ((u >> 16) & 1);
    return (u16)(u >> 16);
}
__device__ inline unsigned cvtpk_bf16(float a, float b) {
    unsigned r;
    asm("v_cvt_pk_bf16_f32 %0, %1, %2" : "=v"(r) : "v"(a), "v"(b));
    return r;
}

// ---------------------------------------------------------------------------
// PREP: fused {fp32->bf16 conversion} (blocks 0..1023) and {RPE MLPs}
// (blocks 1024..1923). Verified R17.
// ---------------------------------------------------------------------------
#define HS4  115200   // 1800*256/4
#define KV4  524288   // 8192*256/4
#define W4   16384    // 256*256/4
#define CONVB 1024
__global__ __launch_bounds__(256) void prep_kernel(
    const float* __restrict__ hs, const float* __restrict__ kv,
    const float* __restrict__ qw, const float* __restrict__ kw,
    const float* __restrict__ vw,
    const float* __restrict__ ref_pts,
    const float* __restrict__ w1x, const float* __restrict__ b1x,
    const float* __restrict__ w2x,
    const float* __restrict__ w1y, const float* __restrict__ b1y,
    const float* __restrict__ w2y,
    u16* __restrict__ hsbf, u16* __restrict__ kvbf,
    u16* __restrict__ qwbf, u16* __restrict__ kwbf, u16* __restrict__ vwbf,
    float* __restrict__ rpex, float* __restrict__ rpey)
{
    __shared__ f32x4 wpk[RPEH];
    __shared__ float w2t[RPEH][NHEAD];
    __shared__ float2 red[3][4][4][64];

    const int t = threadIdx.x;

    if (blockIdx.x < CONVB) {
        const int total = HS4 + KV4 + 3 * W4;
        for (int g = blockIdx.x * 256 + t; g < total; g += CONVB * 256) {
            const float* s; u16* d; int off;
            if (g < HS4)                       { s = hs; d = hsbf; off = g; }
            else if (g < HS4 + KV4)            { s = kv; d = kvbf; off = g - HS4; }
            else if (g < HS4 + KV4 + W4)       { s = qw; d = qwbf; off = g - HS4 - KV4; }
            else if (g < HS4 + KV4 + 2 * W4)   { s = kw; d = kwbf; off = g - HS4 - KV4 - W4; }
            else                               { s = vw; d = vwbf; off = g - HS4 - KV4 - 2 * W4; }
            f32x4 v = *(const f32x4*)(s + (size_t)off * 4);
            *(u16x4*)(d + (size_t)off * 4) =
                (u16x4){f2bf(v[0]), f2bf(v[1]), f2bf(v[2]), f2bf(v[3])};
        }
        return;
    }

    const int bid = blockIdx.x - CONVB;
    const int m   = bid & 1;
    const int bq0 = (bid >> 1) * 4;

    const float* w1 = m ? w1y : w1x;
    const float* b1 = m ? b1y : b1x;
    const float* w2 = m ? w2y : w2x;
    for (int r = t; r < RPEH; r += 256) {
        float a = w1[r * 2], b = w1[r * 2 + 1];
        wpk[r] = (f32x4){a, b, b1[r], a + b};
    }
    for (int i = t; i < RPEH * NHEAD; i += 256) {
        int h = i >> 9, r = i & 511;
        w2t[r][h] = w2[h * RPEH + r] * LOG2E;
    }
    __syncthreads();

    const int lane = t & 63;
    const int wv   = t >> 6;
    const float p  = (lane + 0.5f) * 16.f;

    float lo[4], hi[4];
    #pragma unroll
    for (int j = 0; j < 4; ++j) {
        const float* q = ref_pts + (size_t)(bq0 + j) * 4;
        float c = m ? q[1] : q[0];
        float s = m ? q[3] : q[2];
        lo[j] = (c - s * 0.5f) * 1024.f;
        hi[j] = (c + s * 0.5f) * 1024.f;
    }

    float2 acc[4][4] = {};
    const int r0 = wv * 128;
    #pragma unroll 4
    for (int rr = 0; rr < 128; ++rr) {
        int r = r0 + rr;
        f32x4 W  = wpk[r];
        f32x4 u0 = *(const f32x4*)&w2t[r][0];
        f32x4 u1 = *(const f32x4*)&w2t[r][4];
        float bp = W[3] * p;
        #pragma unroll
        for (int tk = 0; tk < 4; ++tk) {
            float al  = W[0] * lo[tk] + W[1] * hi[tk] + W[2];
            float hid = fmaxf(al - bp, 0.f);
            acc[tk][0].x += u0[0] * hid;  acc[tk][0].y += u0[1] * hid;
            acc[tk][1].x += u0[2] * hid;  acc[tk][1].y += u0[3] * hid;
            acc[tk][2].x += u1[0] * hid;  acc[tk][2].y += u1[1] * hid;
            acc[tk][3].x += u1[2] * hid;  acc[tk][3].y += u1[3] * hid;
        }
    }

    if (wv > 0) {
        #pragma unroll
        for (int tk = 0; tk < 4; ++tk)
            #pragma unroll
            for (int j = 0; j < 4; ++j)
                red[wv - 1][tk][j][lane] = acc[tk][j];
    }
    __syncthreads();
    if (wv == 0) {
        float* outp = m ? rpey : rpex;
        #pragma unroll
        for (int tk = 0; tk < 4; ++tk) {
            size_t base = (size_t)(bq0 + tk) * (NHEAD * GRID) + lane;
            #pragma unroll
            for (int j = 0; j < 4; ++j) {
                float2 s0 = red[0][tk][j][lane];
                float2 s1 = red[1][tk][j][lane];
                float2 s2 = red[2][tk][j][lane];
                float sx = acc[tk][j].x + s0.x + s1.x + s2.x;
                float sy = acc[tk][j].y + s0.y + s1.y + s2.y;
                outp[base + (2 * j) * GRID]     = sx;
                outp[base + (2 * j + 1) * GRID] = sy;
            }
        }
    }
}

// ---------------------------------------------------------------------------
// bf16 MFMA projection GEMM, Q/K/V fused (verified R17).
// ---------------------------------------------------------------------------
__global__ __launch_bounds__(256) void proj_mfma(
    const u16* __restrict__ hsbf, const u16* __restrict__ kvbf,
    const u16* __restrict__ qwbf, const float* __restrict__ q_b,
    const u16* __restrict__ kwbf, const float* __restrict__ k_b,
    const u16* __restrict__ vwbf, const float* __restrict__ v_b,
    u16* __restrict__ Qbf, u16* __restrict__ Kbf, u16* __restrict__ Vt,
    float scaleQ)
{
    __shared__ u16 Abuf[2][4096];
    __shared__ u16 Bbuf[2][4096];

    const u16* A; const u16* W; const float* bias;
    u16* outRow = nullptr; bool vt = false; int M; float scale = 1.f;
    if (blockIdx.z == 0)      { A = kvbf; W = kwbf; bias = k_b; outRow = Kbf; M = NB * NKV; }
    else if (blockIdx.z == 1) { A = kvbf; W = vwbf; bias = v_b; vt = true;   M = NB * NKV; }
    else {
        if (blockIdx.x >= 15) return;
        A = hsbf; W = qwbf; bias = q_b; outRow = Qbf; M = NB * NQ; scale = scaleQ;
    }

    const int t    = threadIdx.x;
    const int lane = t & 63;
    const int w    = t >> 6;
    const int wm   = w >> 1, wn = w & 1;
    const int m0   = blockIdx.x * 128;
    const int n0   = blockIdx.y * 128;

    const int r0 = t >> 2, c0 = t & 3;
    const int r1 = r0 + 64;
    const int s0 = r0 * 4 + (c0 ^ (r0 & 3));
    const int s1 = r1 * 4 + (c0 ^ (r1 & 3));
    const u16* Arow0 = A + (size_t)(m0 + r0) * DIMM + c0 * 8;
    const u16* Arow1 = A + (size_t)(m0 + r1) * DIMM + c0 * 8;
    const u16* Wrow0 = W + (size_t)(n0 + r0) * DIMM + c0 * 8;
    const u16* Wrow1 = W + (size_t)(n0 + r1) * DIMM + c0 * 8;

    const int fr = lane & 15, fkc = lane >> 4;
    int aslot[4], bslot[4];
    #pragma unroll
    for (int f = 0; f < 4; ++f) {
        int ar = wm * 64 + f * 16 + fr;
        int br = wn * 64 + f * 16 + fr;
        aslot[f] = ar * 4 + (fkc ^ (ar & 3));
        bslot[f] = br * 4 + (fkc ^ (br & 3));
    }
    float bv[4];
    #pragma unroll
    for (int f = 0; f < 4; ++f) bv[f] = bias[n0 + wn * 64 + f * 16 + fr];

    f32x4 acc[4][4] = {};

    {
        short8 a0 = *(const short8*)(Arow0);
        short8 a1 = *(const short8*)(Arow1);
        short8 b0 = *(const short8*)(Wrow0);
        short8 b1 = *(const short8*)(Wrow1);
        *(short8*)&Abuf[0][s0 * 8] = a0;
        *(short8*)&Abuf[0][s1 * 8] = a1;
        *(short8*)&Bbuf[0][s0 * 8] = b0;
        *(short8*)&Bbuf[0][s1 * 8] = b1;
    }
    __syncthreads();

    int cur = 0;
    for (int kt = 0; kt < 8; ++kt) {
        short8 na0, na1, nb0, nb1;
        if (kt < 7) {
            int ko = (kt + 1) * 32;
            na0 = *(const short8*)(Arow0 + ko);
            na1 = *(const short8*)(Arow1 + ko);
            nb0 = *(const short8*)(Wrow0 + ko);
            nb1 = *(const short8*)(Wrow1 + ko);
        }
        short8 af[4], bf[4];
        #pragma unroll
        for (int f = 0; f < 4; ++f) {
            af[f] = *(const short8*)&Abuf[cur][aslot[f] * 8];
            bf[f] = *(const short8*)&Bbuf[cur][bslot[f] * 8];
        }
        #pragma unroll
        for (int i = 0; i < 4; ++i)
            #pragma unroll
            for (int j = 0; j < 4; ++j)
                acc[i][j] = __builtin_amdgcn_mfma_f32_16x16x32_bf16(af[i], bf[j], acc[i][j], 0, 0, 0);
        if (kt < 7) {
            *(short8*)&Abuf[cur ^ 1][s0 * 8] = na0;
            *(short8*)&Abuf[cur ^ 1][s1 * 8] = na1;
            *(short8*)&Bbuf[cur ^ 1][s0 * 8] = nb0;
            *(short8*)&Bbuf[cur ^ 1][s1 * 8] = nb1;
        }
        __syncthreads();
        cur ^= 1;
    }

    #pragma unroll
    for (int i = 0; i < 4; ++i) {
        int mbase = m0 + wm * 64 + i * 16 + 4 * fkc;
        #pragma unroll
        for (int j = 0; j < 4; ++j) {
            int n = n0 + wn * 64 + j * 16 + fr;
            #pragma unroll
            for (int r = 0; r < 4; ++r) {
                int gm = mbase + r;
                if (gm < M) {
                    float v = (acc[i][j][r] + bv[j]) * scale;
                    if (!vt) {
                        outRow[(size_t)gm * DIMM + n] = f2bf(v);
                    } else {
                        int bb = gm >> 12, kvi = gm & 4095;
                        int hh = n >> 5, dd = n & 31;
                        Vt[(size_t)((bb * NHEAD + hh) * HD + dd) * NKV + kvi] = f2bf(v);
                    }
                }
            }
        }
    }
}

// ---------------------------------------------------------------------------
// MFMA attention, KV-split x4, KB=128 per iteration (x2 unroll of the
// verified 64-key tile; 8 iterations instead of 16 -> half the barriers,
// reduces, rescale checks). Same index maps; x-bias repeats every 64 keys;
// kt 0..3 use grid row 2t, kt 4..7 use 2t+1 (ry loaded from global, L1-hot).
// ---------------------------------------------------------------------------
__global__ __launch_bounds__(256) void attn_mfma(
    const u16* __restrict__ Qbf, const u16* __restrict__ Kbf,
    const u16* __restrict__ Vt,
    const float* __restrict__ RX, const float* __restrict__ RY,
    const int* __restrict__ mask,
    float* __restrict__ pctx, float2* __restrict__ pml)
{
    constexpr int KSEG = NKV / SPLIT;     // 1024 keys per block
    constexpr int NIT  = KSEG / 128;      // 8 iterations of 128 keys
    __shared__ short8 kbuf[2][8][64];     // 16 KB
    __shared__ short8 vbuf[2][8][64];     // 16 KB
    __shared__ unsigned pbuf[4][64][4];   // 4 KB
    __shared__ float mbuf[2][128];        // 1 KB

    const int tid  = threadIdx.x;
    const int lane = tid & 63;
    const int w    = tid >> 6;
    const int q15  = lane & 15;
    const int g    = lane >> 4;
    const int qt = blockIdx.x, h = blockIdx.y;
    const int b  = blockIdx.z / SPLIT;
    const int sp = blockIdx.z % SPLIT;
    const int q0 = qt * 64;
    const int wq = w * 16 + q15;
    const int gq = q0 + wq;
    const bool qok = gq < NQ;
    const int kv0g = sp * KSEG;

    float rxr[16];
    {
        const float* rxrow = RX + (size_t)(b * NQ + (qok ? gq : 0)) * (NHEAD * GRID) + h * GRID;
        #pragma unroll
        for (int kt = 0; kt < 4; ++kt)
            #pragma unroll
            for (int r = 0; r < 4; ++r)
                rxr[kt * 4 + r] = qok ? rxrow[16 * kt + 4 * g + r] : 0.f;
    }
    const float* yrow = RY + (size_t)(b * NQ + (qok ? gq : 0)) * (NHEAD * GRID) + h * GRID + sp * 16;

    short8 qf = *(const short8*)(Qbf + ((size_t)(b * NQ + gq)) * DIMM + h * HD + 8 * g);

    // staging maps (two K rows + two V chunks per thread per 128-key tile)
    const int sr = tid >> 2, sc = tid & 3;      // K rows sr, sr+64
    const int vd = tid >> 3, vc = tid & 7;      // V chunks vc, vc+8
    const size_t kbase = ((size_t)(b * NKV + kv0g + sr)) * DIMM + h * HD + 8 * sc;
    const size_t vbase = ((size_t)((b * NHEAD + h) * HD + vd)) * NKV + kv0g + 8 * vc;

    // prologue: stage 128-key tile 0
    {
        kbuf[0][sr >> 4][(sr & 15) + 16 * sc] = *(const short8*)(Kbf + kbase);
        int sr2 = sr + 64;
        kbuf[0][sr2 >> 4][(sr2 & 15) + 16 * sc] = *(const short8*)(Kbf + kbase + (size_t)64 * DIMM);
        vbuf[0][(vc >> 2) * 2 + (vd >> 4)][16 * (vc & 3) + (vd & 15)] = *(const short8*)(Vt + vbase);
        int vc2 = vc + 8;
        vbuf[0][(vc2 >> 2) * 2 + (vd >> 4)][16 * (vc2 & 3) + (vd & 15)] = *(const short8*)(Vt + vbase + 64);
        if (tid < 128) mbuf[0][tid] = -(100.f * LOG2E) * (float)mask[b * NKV + kv0g + tid];
    }
    __syncthreads();

    f32x4 cacc0 = {0.f, 0.f, 0.f, 0.f};
    f32x4 cacc1 = {0.f, 0.f, 0.f, 0.f};
    float m_run = -1e30f, l_run = 0.f;
    int cur = 0;

    for (int t = 0; t < NIT; ++t) {
        short8 rk0 = {}, rk1 = {}, rv0 = {}, rv1 = {};
        float rm = 0.f;
        if (t < NIT - 1) {
            size_t kvn = (size_t)(t + 1) * 128;
            rk0 = *(const short8*)(Kbf + kbase + kvn * DIMM);
            rk1 = *(const short8*)(Kbf + kbase + (kvn + 64) * DIMM);
            rv0 = *(const short8*)(Vt + vbase + kvn);
            rv1 = *(const short8*)(Vt + vbase + kvn + 64);
            if (tid < 128) rm = -(100.f * LOG2E) * (float)mask[b * NKV + kv0g + kvn + tid];
        }
        float ryb0 = qok ? yrow[2 * t] : 0.f;
        float ryb1 = qok ? yrow[2 * t + 1] : 0.f;

        // ---- QK^T over 128 keys ----
        f32x4 zero = {0.f, 0.f, 0.f, 0.f};
        f32x4 s[8];
        __builtin_amdgcn_s_setprio(1);
        #pragma unroll
        for (int kt = 0; kt < 8; ++kt)
            s[kt] = __builtin_amdgcn_mfma_f32_16x16x32_bf16(kbuf[cur][kt][lane], qf, zero, 0, 0, 0);
        __builtin_amdgcn_s_setprio(0);

        // ---- bias (x-pattern repeats every 64 keys) ----
        #pragma unroll
        for (int kt = 0; kt < 8; ++kt) {
            float ryb = (kt < 4) ? ryb0 : ryb1;
            #pragma unroll
            for (int r = 0; r < 4; ++r)
                s[kt][r] += rxr[(kt & 3) * 4 + r] + ryb + mbuf[cur][16 * kt + 4 * g + r];
        }

        // ---- online softmax over 128 keys (one reduce/rescale per iter) ----
        float mk[8];
        #pragma unroll
        for (int kt = 0; kt < 8; ++kt)
            mk[kt] = fmaxf(fmaxf(s[kt][0], s[kt][1]), fmaxf(s[kt][2], s[kt][3]));
        float mloc = fmaxf(fmaxf(fmaxf(mk[0], mk[1]), fmaxf(mk[2], mk[3])),
                           fmaxf(fmaxf(mk[4], mk[5]), fmaxf(mk[6], mk[7])));
        mloc = fmaxf(mloc, __shfl_xor(mloc, 16));
        mloc = fmaxf(mloc, __shfl_xor(mloc, 32));

        if (!__all(mloc <= m_run + 8.f)) {
            float mnew = fmaxf(m_run, mloc);
            float fsc  = exp2f(m_run - mnew);
            l_run *= fsc;
            cacc0 *= fsc;
            cacc1 *= fsc;
            m_run = mnew;
        }

        float psum = 0.f;
        #pragma unroll
        for (int kt = 0; kt < 8; ++kt)
            #pragma unroll
            for (int r = 0; r < 4; ++r) {
                float pv = exp2f(s[kt][r] - m_run);
                s[kt][r] = pv;
                psum += pv;
            }
        psum += __shfl_xor(psum, 16);
        psum += __shfl_xor(psum, 32);
        l_run += psum;

        // ---- pack + PV, one 32-key group at a time ----
        __builtin_amdgcn_s_setprio(1);
        #pragma unroll
        for (int sk = 0; sk < 4; ++sk) {
            #pragma unroll
            for (int kk = 0; kk < 2; ++kk) {
                int kt = sk * 2 + kk;
                unsigned d0 = cvtpk_bf16(s[kt][0], s[kt][1]);
                unsigned d1 = cvtpk_bf16(s[kt][2], s[kt][3]);
                int lt = 16 * ((2 * kt + (g >> 1)) & 3) + q15;
                uint2v* dst = (uint2v*)&pbuf[w][lt][2 * (g & 1)];
                *dst = (uint2v){d0, d1};
            }
            short8 pf = *(const short8*)&pbuf[w][lane][0];
            cacc0 = __builtin_amdgcn_mfma_f32_16x16x32_bf16(vbuf[cur][sk * 2 + 0][lane], pf, cacc0, 0, 0, 0);
            cacc1 = __builtin_amdgcn_mfma_f32_16x16x32_bf16(vbuf[cur][sk * 2 + 1][lane], pf, cacc1, 0, 0, 0);
        }
        __builtin_amdgcn_s_setprio(0);

        // ---- write staged tile ----
        if (t < NIT - 1) {
            kbuf[cur ^ 1][sr >> 4][(sr & 15) + 16 * sc] = rk0;
            int sr2 = sr + 64;
            kbuf[cur ^ 1][sr2 >> 4][(sr2 & 15) + 16 * sc] = rk1;
            vbuf[cur ^ 1][(vc >> 2) * 2 + (vd >> 4)][16 * (vc & 3) + (vd & 15)] = rv0;
            int vc2 = vc + 8;
            vbuf[cur ^ 1][(vc2 >> 2) * 2 + (vd >> 4)][16 * (vc2 & 3) + (vd & 15)] = rv1;
            if (tid < 128) mbuf[cur ^ 1][tid] = rm;
        }
        __syncthreads();
        cur ^= 1;
    }

    size_t prow = (size_t)(sp * NB + b) * NQP + gq;
    float* pc = pctx + prow * DIMM + h * HD;
    #pragma unroll
    for (int r = 0; r < 4; ++r) {
        pc[4 * g + r]      = cacc0[r];
        pc[16 + 4 * g + r] = cacc1[r];
    }
    if (g == 0) {
        float2 v; v.x = m_run; v.y = l_run;
        pml[prow * NHEAD + h] = v;
    }
}

// ---------------------------------------------------------------------------
// Combine the 4 KV-split partials (log2-domain m -> exp2 weights).
// ---------------------------------------------------------------------------
__global__ __launch_bounds__(256) void attn_reduce(
    const float* __restrict__ pctx, const float2* __restrict__ pml,
    float* __restrict__ CTX)
{
    const int bq = blockIdx.x;
    const int b = bq / NQ, q = bq - b * NQ;
    const int c = threadIdx.x;
    const int h = c >> 5;

    float m[SPLIT], l[SPLIT];
    #pragma unroll
    for (int sp = 0; sp < SPLIT; ++sp) {
        float2 v = pml[((size_t)(sp * NB + b) * NQP + q) * NHEAD + h];
        m[sp] = v.x; l[sp] = v.y;
    }
    float ms = fmaxf(fmaxf(m[0], m[1]), fmaxf(m[2], m[3]));
    float L = 0.f, acc = 0.f;
    #pragma unroll
    for (int sp = 0; sp < SPLIT; ++sp) {
        float wgt = exp2f(m[sp] - ms);
        L   += wgt * l[sp];
        acc += wgt * pctx[((size_t)(sp * NB + b) * NQP + q) * DIMM + c];
    }
    CTX[(size_t)bq * DIMM + c] = acc / L;
}

// ---------------------------------------------------------------------------
// fp32 GEMM for the output projection (unchanged, verified).
// ---------------------------------------------------------------------------
__global__ __launch_bounds__(256) void gemm_bias_f32(
    const float* __restrict__ A, const float* __restrict__ W,
    const float* __restrict__ bias, float* __restrict__ C,
    int M, int N, int K)
{
    __shared__ float As[32][33];
    __shared__ float Ws[32][33];
    const int t  = threadIdx.x;
    const int tr = t >> 4;
    const int tc = t & 15;
    const int brow = blockIdx.y * 32;
    const int bcol = blockIdx.x * 32;
    float acc00 = 0.f, acc01 = 0.f, acc10 = 0.f, acc11 = 0.f;

    for (int kt = 0; kt < K; kt += 32) {
        #pragma unroll
        for (int i = 0; i < 4; ++i) {
            int idx = t + i * 256;
            int r = idx >> 5, c = idx & 31;
            int gr = brow + r;
            As[r][c] = (gr < M) ? A[(size_t)gr * K + kt + c] : 0.f;
            Ws[r][c] = W[(size_t)(bcol + r) * K + kt + c];
        }
        __syncthreads();
        #pragma unroll 8
        for (int k = 0; k < 32; ++k) {
            float a0 = As[tr * 2][k], a1 = As[tr * 2 + 1][k];
            float w0 = Ws[tc * 2][k], w1 = Ws[tc * 2 + 1][k];
            acc00 += a0 * w0; acc01 += a0 * w1;
            acc10 += a1 * w0; acc11 += a1 * w1;
        }
        __syncthreads();
    }
    int gc0 = bcol + tc * 2, gc1 = gc0 + 1;
    int gr0 = brow + tr * 2, gr1 = gr0 + 1;
    if (gr0 < M) {
        C[(size_t)gr0 * N + gc0] = acc00 + bias[gc0];
        C[(size_t)gr0 * N + gc1] = acc01 + bias[gc1];
    }
    if (gr1 < M) {
        C[(size_t)gr1 * N + gc0] = acc10 + bias[gc0];
        C[(size_t)gr1 * N + gc1] = acc11 + bias[gc1];
    }
}

// ---------------------------------------------------------------------------
extern "C" void kernel_launch(void* const* d_in, const int* in_sizes, int n_in,
                              void* d_out, int out_size, void* d_ws, size_t ws_size,
                              hipStream_t stream)
{
    const float* hs   = (const float*)d_in[0];
    const float* rp   = (const float*)d_in[1];
    const float* kv   = (const float*)d_in[2];
    const int*   msk  = (const int*)d_in[4];
    const float* m1w1 = (const float*)d_in[5];
    const float* m1b1 = (const float*)d_in[6];
    const float* m1w2 = (const float*)d_in[7];
    const float* m2w1 = (const float*)d_in[8];
    const float* m2b1 = (const float*)d_in[9];
    const float* m2w2 = (const float*)d_in[10];
    const float* q_w  = (const float*)d_in[11];
    const float* q_b  = (const float*)d_in[12];
    const float* k_w  = (const float*)d_in[13];
    const float* k_b  = (const float*)d_in[14];
    const float* v_w  = (const float*)d_in[15];
    const float* v_b  = (const float*)d_in[16];
    const float* o_w  = (const float*)d_in[17];
    const float* o_b  = (const float*)d_in[18];
    float* out = (float*)d_out;

    char* p = (char*)d_ws;
    float* RX   = (float*)p; p += (size_t)NB * NQ * NHEAD * GRID * 4;
    float* RY   = (float*)p; p += (size_t)NB * NQ * NHEAD * GRID * 4;
    float* CTX  = (float*)p; p += (size_t)NB * NQ * DIMM * 4;
    u16*   Qbf  = (u16*)p;   p += (size_t)1920 * DIMM * 2;
    u16*   Kbf  = (u16*)p;   p += (size_t)NB * NKV * DIMM * 2;
    u16*   Vt   = (u16*)p;   p += (size_t)NB * NHEAD * HD * NKV * 2;

    // union region: {bf16 conv buffers} (prep..proj) / {attn partials} (attn..reduce)
    char* u = p;
    u16* hsbf = (u16*)u;
    u16* kvbf = hsbf + (size_t)1920 * DIMM;
    u16* qwbf = kvbf + (size_t)NB * NKV * DIMM;
    u16* kwbf = qwbf + (size_t)DIMM * DIMM;
    u16* vwbf = kwbf + (size_t)DIMM * DIMM;
    float*  pctx = (float*)u;
    float2* pml  = (float2*)(pctx + (size_t)SPLIT * NB * NQP * DIMM);

    const float scale = 0.17677669529663687f * LOG2E;  // 32^-0.5 * log2(e)

    // 1) fused conversion + RPE MLPs
    prep_kernel<<<CONVB + 900, 256, 0, stream>>>(
        hs, kv, q_w, k_w, v_w, rp, m1w1, m1b1, m1w2, m2w1, m2b1, m2w2,
        hsbf, kvbf, qwbf, kwbf, vwbf, RX, RY);

    // 2) Q + K + V projections in one launch (z=0 K, z=1 V, z=2 Q)
    proj_mfma<<<dim3(64, 2, 3), 256, 0, stream>>>(
        hsbf, kvbf, qwbf, q_b, kwbf, k_b, vwbf, v_b, Qbf, Kbf, Vt, scale);

    // 3) MFMA attention, KV-split x4, KB=128 iterations
    attn_mfma<<<dim3((NQ + 63) / 64, NHEAD, NB * SPLIT), 256, 0, stream>>>(
        Qbf, Kbf, Vt, RX, RY, msk, pctx, pml);

    // 4) combine partials
    attn_reduce<<<NB * NQ, 256, 0, stream>>>(pctx, pml, CTX);

    // 5) Output projection (fp32)
    gemm_bias_f32<<<dim3(DIMM / 32, (NB * NQ + 31) / 32), 256, 0, stream>>>(
        CTX, o_w, o_b, out, NB * NQ, DIMM, DIMM);
}

// Round 19
// 129.294 us; speedup vs baseline: 1.0660x; 1.0660x over previous
//
#include <hip/hip_runtime.h>
#include <math.h>

#define NB    2
#define NQ    900
#define NQP   960
#define NKV   4096
#define DIMM  256
#define NHEAD 8
#define HD    32
#define RPEH  512
#define GRID  64
#define SPLIT 4

#define LOG2E 1.4426950408889634f

typedef short short8 __attribute__((ext_vector_type(8)));
typedef float f32x4 __attribute__((ext_vector_type(4)));
typedef unsigned uint2v __attribute__((ext_vector_type(2)));
typedef unsigned short u16;
typedef unsigned short u16x4 __attribute__((ext_vector_type(4)));

__device__ inline u16 f2bf(float f) {
    unsigned u = __builtin_bit_cast(unsigned, f);
    u += 0x7fff + ((u >> 16) & 1);
    return (u16)(u >> 16);
}
__device__ inline unsigned cvtpk_bf16(float a, float b) {
    unsigned r;
    asm("v_cvt_pk_bf16_f32 %0, %1, %2" : "=v"(r) : "v"(a), "v"(b));
    return r;
}

// ---------------------------------------------------------------------------
// PREP: fused {fp32->bf16 conversion} (blocks 0..1023) and {RPE MLPs}
// (blocks 1024..1923). Verified R17.
// ---------------------------------------------------------------------------
#define HS4  115200   // 1800*256/4
#define KV4  524288   // 8192*256/4
#define W4   16384    // 256*256/4
#define CONVB 1024
__global__ __launch_bounds__(256) void prep_kernel(
    const float* __restrict__ hs, const float* __restrict__ kv,
    const float* __restrict__ qw, const float* __restrict__ kw,
    const float* __restrict__ vw,
    const float* __restrict__ ref_pts,
    const float* __restrict__ w1x, const float* __restrict__ b1x,
    const float* __restrict__ w2x,
    const float* __restrict__ w1y, const float* __restrict__ b1y,
    const float* __restrict__ w2y,
    u16* __restrict__ hsbf, u16* __restrict__ kvbf,
    u16* __restrict__ qwbf, u16* __restrict__ kwbf, u16* __restrict__ vwbf,
    float* __restrict__ rpex, float* __restrict__ rpey)
{
    __shared__ f32x4 wpk[RPEH];
    __shared__ float w2t[RPEH][NHEAD];
    __shared__ float2 red[3][4][4][64];

    const int t = threadIdx.x;

    if (blockIdx.x < CONVB) {
        const int total = HS4 + KV4 + 3 * W4;
        for (int g = blockIdx.x * 256 + t; g < total; g += CONVB * 256) {
            const float* s; u16* d; int off;
            if (g < HS4)                       { s = hs; d = hsbf; off = g; }
            else if (g < HS4 + KV4)            { s = kv; d = kvbf; off = g - HS4; }
            else if (g < HS4 + KV4 + W4)       { s = qw; d = qwbf; off = g - HS4 - KV4; }
            else if (g < HS4 + KV4 + 2 * W4)   { s = kw; d = kwbf; off = g - HS4 - KV4 - W4; }
            else                               { s = vw; d = vwbf; off = g - HS4 - KV4 - 2 * W4; }
            f32x4 v = *(const f32x4*)(s + (size_t)off * 4);
            *(u16x4*)(d + (size_t)off * 4) =
                (u16x4){f2bf(v[0]), f2bf(v[1]), f2bf(v[2]), f2bf(v[3])};
        }
        return;
    }

    const int bid = blockIdx.x - CONVB;
    const int m   = bid & 1;
    const int bq0 = (bid >> 1) * 4;

    const float* w1 = m ? w1y : w1x;
    const float* b1 = m ? b1y : b1x;
    const float* w2 = m ? w2y : w2x;
    for (int r = t; r < RPEH; r += 256) {
        float a = w1[r * 2], b = w1[r * 2 + 1];
        wpk[r] = (f32x4){a, b, b1[r], a + b};
    }
    for (int i = t; i < RPEH * NHEAD; i += 256) {
        int h = i >> 9, r = i & 511;
        w2t[r][h] = w2[h * RPEH + r] * LOG2E;
    }
    __syncthreads();

    const int lane = t & 63;
    const int wv   = t >> 6;
    const float p  = (lane + 0.5f) * 16.f;

    float lo[4], hi[4];
    #pragma unroll
    for (int j = 0; j < 4; ++j) {
        const float* q = ref_pts + (size_t)(bq0 + j) * 4;
        float c = m ? q[1] : q[0];
        float s = m ? q[3] : q[2];
        lo[j] = (c - s * 0.5f) * 1024.f;
        hi[j] = (c + s * 0.5f) * 1024.f;
    }

    float2 acc[4][4] = {};
    const int r0 = wv * 128;
    #pragma unroll 4
    for (int rr = 0; rr < 128; ++rr) {
        int r = r0 + rr;
        f32x4 W  = wpk[r];
        f32x4 u0 = *(const f32x4*)&w2t[r][0];
        f32x4 u1 = *(const f32x4*)&w2t[r][4];
        float bp = W[3] * p;
        #pragma unroll
        for (int tk = 0; tk < 4; ++tk) {
            float al  = W[0] * lo[tk] + W[1] * hi[tk] + W[2];
            float hid = fmaxf(al - bp, 0.f);
            acc[tk][0].x += u0[0] * hid;  acc[tk][0].y += u0[1] * hid;
            acc[tk][1].x += u0[2] * hid;  acc[tk][1].y += u0[3] * hid;
            acc[tk][2].x += u1[0] * hid;  acc[tk][2].y += u1[1] * hid;
            acc[tk][3].x += u1[2] * hid;  acc[tk][3].y += u1[3] * hid;
        }
    }

    if (wv > 0) {
        #pragma unroll
        for (int tk = 0; tk < 4; ++tk)
            #pragma unroll
            for (int j = 0; j < 4; ++j)
                red[wv - 1][tk][j][lane] = acc[tk][j];
    }
    __syncthreads();
    if (wv == 0) {
        float* outp = m ? rpey : rpex;
        #pragma unroll
        for (int tk = 0; tk < 4; ++tk) {
            size_t base = (size_t)(bq0 + tk) * (NHEAD * GRID) + lane;
            #pragma unroll
            for (int j = 0; j < 4; ++j) {
                float2 s0 = red[0][tk][j][lane];
                float2 s1 = red[1][tk][j][lane];
                float2 s2 = red[2][tk][j][lane];
                float sx = acc[tk][j].x + s0.x + s1.x + s2.x;
                float sy = acc[tk][j].y + s0.y + s1.y + s2.y;
                outp[base + (2 * j) * GRID]     = sx;
                outp[base + (2 * j + 1) * GRID] = sy;
            }
        }
    }
}

// ---------------------------------------------------------------------------
// bf16 MFMA projection GEMM, Q/K/V fused (verified R17).
// ---------------------------------------------------------------------------
__global__ __launch_bounds__(256) void proj_mfma(
    const u16* __restrict__ hsbf, const u16* __restrict__ kvbf,
    const u16* __restrict__ qwbf, const float* __restrict__ q_b,
    const u16* __restrict__ kwbf, const float* __restrict__ k_b,
    const u16* __restrict__ vwbf, const float* __restrict__ v_b,
    u16* __restrict__ Qbf, u16* __restrict__ Kbf, u16* __restrict__ Vt,
    float scaleQ)
{
    __shared__ u16 Abuf[2][4096];
    __shared__ u16 Bbuf[2][4096];

    const u16* A; const u16* W; const float* bias;
    u16* outRow = nullptr; bool vt = false; int M; float scale = 1.f;
    if (blockIdx.z == 0)      { A = kvbf; W = kwbf; bias = k_b; outRow = Kbf; M = NB * NKV; }
    else if (blockIdx.z == 1) { A = kvbf; W = vwbf; bias = v_b; vt = true;   M = NB * NKV; }
    else {
        if (blockIdx.x >= 15) return;
        A = hsbf; W = qwbf; bias = q_b; outRow = Qbf; M = NB * NQ; scale = scaleQ;
    }

    const int t    = threadIdx.x;
    const int lane = t & 63;
    const int w    = t >> 6;
    const int wm   = w >> 1, wn = w & 1;
    const int m0   = blockIdx.x * 128;
    const int n0   = blockIdx.y * 128;

    const int r0 = t >> 2, c0 = t & 3;
    const int r1 = r0 + 64;
    const int s0 = r0 * 4 + (c0 ^ (r0 & 3));
    const int s1 = r1 * 4 + (c0 ^ (r1 & 3));
    const u16* Arow0 = A + (size_t)(m0 + r0) * DIMM + c0 * 8;
    const u16* Arow1 = A + (size_t)(m0 + r1) * DIMM + c0 * 8;
    const u16* Wrow0 = W + (size_t)(n0 + r0) * DIMM + c0 * 8;
    const u16* Wrow1 = W + (size_t)(n0 + r1) * DIMM + c0 * 8;

    const int fr = lane & 15, fkc = lane >> 4;
    int aslot[4], bslot[4];
    #pragma unroll
    for (int f = 0; f < 4; ++f) {
        int ar = wm * 64 + f * 16 + fr;
        int br = wn * 64 + f * 16 + fr;
        aslot[f] = ar * 4 + (fkc ^ (ar & 3));
        bslot[f] = br * 4 + (fkc ^ (br & 3));
    }
    float bv[4];
    #pragma unroll
    for (int f = 0; f < 4; ++f) bv[f] = bias[n0 + wn * 64 + f * 16 + fr];

    f32x4 acc[4][4] = {};

    {
        short8 a0 = *(const short8*)(Arow0);
        short8 a1 = *(const short8*)(Arow1);
        short8 b0 = *(const short8*)(Wrow0);
        short8 b1 = *(const short8*)(Wrow1);
        *(short8*)&Abuf[0][s0 * 8] = a0;
        *(short8*)&Abuf[0][s1 * 8] = a1;
        *(short8*)&Bbuf[0][s0 * 8] = b0;
        *(short8*)&Bbuf[0][s1 * 8] = b1;
    }
    __syncthreads();

    int cur = 0;
    for (int kt = 0; kt < 8; ++kt) {
        short8 na0, na1, nb0, nb1;
        if (kt < 7) {
            int ko = (kt + 1) * 32;
            na0 = *(const short8*)(Arow0 + ko);
            na1 = *(const short8*)(Arow1 + ko);
            nb0 = *(const short8*)(Wrow0 + ko);
            nb1 = *(const short8*)(Wrow1 + ko);
        }
        short8 af[4], bf[4];
        #pragma unroll
        for (int f = 0; f < 4; ++f) {
            af[f] = *(const short8*)&Abuf[cur][aslot[f] * 8];
            bf[f] = *(const short8*)&Bbuf[cur][bslot[f] * 8];
        }
        #pragma unroll
        for (int i = 0; i < 4; ++i)
            #pragma unroll
            for (int j = 0; j < 4; ++j)
                acc[i][j] = __builtin_amdgcn_mfma_f32_16x16x32_bf16(af[i], bf[j], acc[i][j], 0, 0, 0);
        if (kt < 7) {
            *(short8*)&Abuf[cur ^ 1][s0 * 8] = na0;
            *(short8*)&Abuf[cur ^ 1][s1 * 8] = na1;
            *(short8*)&Bbuf[cur ^ 1][s0 * 8] = nb0;
            *(short8*)&Bbuf[cur ^ 1][s1 * 8] = nb1;
        }
        __syncthreads();
        cur ^= 1;
    }

    #pragma unroll
    for (int i = 0; i < 4; ++i) {
        int mbase = m0 + wm * 64 + i * 16 + 4 * fkc;
        #pragma unroll
        for (int j = 0; j < 4; ++j) {
            int n = n0 + wn * 64 + j * 16 + fr;
            #pragma unroll
            for (int r = 0; r < 4; ++r) {
                int gm = mbase + r;
                if (gm < M) {
                    float v = (acc[i][j][r] + bv[j]) * scale;
                    if (!vt) {
                        outRow[(size_t)gm * DIMM + n] = f2bf(v);
                    } else {
                        int bb = gm >> 12, kvi = gm & 4095;
                        int hh = n >> 5, dd = n & 31;
                        Vt[(size_t)((bb * NHEAD + hh) * HD + dd) * NKV + kvi] = f2bf(v);
                    }
                }
            }
        }
    }
}

// ---------------------------------------------------------------------------
// MFMA attention, KV-split x4 (R15/R17 verified: LDS staging, log2 domain,
// cvt_pk pack, defer-max). The measured structural floor for this schedule.
// ---------------------------------------------------------------------------
__global__ __launch_bounds__(256) void attn_mfma(
    const u16* __restrict__ Qbf, const u16* __restrict__ Kbf,
    const u16* __restrict__ Vt,
    const float* __restrict__ RX, const float* __restrict__ RY,
    const int* __restrict__ mask,
    float* __restrict__ pctx, float2* __restrict__ pml)
{
    constexpr int KSEG = NKV / SPLIT;     // 1024 keys per block
    constexpr int NTS  = KSEG / 64;       // 16 tiles
    __shared__ short8 kbuf[2][4][64];
    __shared__ short8 vbuf[2][4][64];
    __shared__ unsigned pbuf[4][64][4];   // halved: one k-half at a time
    __shared__ float ry_s[NTS][68];
    __shared__ float mbuf[2][64];

    const int tid  = threadIdx.x;
    const int lane = tid & 63;
    const int w    = tid >> 6;
    const int q15  = lane & 15;
    const int g    = lane >> 4;
    const int qt = blockIdx.x, h = blockIdx.y;
    const int b  = blockIdx.z / SPLIT;
    const int sp = blockIdx.z % SPLIT;
    const int q0 = qt * 64;
    const int wq = w * 16 + q15;
    const int gq = q0 + wq;
    const bool qok = gq < NQ;
    const int kv0g = sp * KSEG;

    float rxr[16];
    {
        const float* rxrow = RX + (size_t)(b * NQ + (qok ? gq : 0)) * (NHEAD * GRID) + h * GRID;
        #pragma unroll
        for (int kt = 0; kt < 4; ++kt)
            #pragma unroll
            for (int r = 0; r < 4; ++r)
                rxr[kt * 4 + r] = qok ? rxrow[16 * kt + 4 * g + r] : 0.f;
    }
    for (int idx = tid; idx < NTS * 64; idx += 256) {
        int y = idx & (NTS - 1), q = idx / NTS;
        int gq2 = q0 + q;
        ry_s[y][q] = (gq2 < NQ)
            ? RY[(size_t)(b * NQ + gq2) * (NHEAD * GRID) + h * GRID + sp * NTS + y] : 0.f;
    }

    short8 qf = *(const short8*)(Qbf + ((size_t)(b * NQ + gq)) * DIMM + h * HD + 8 * g);

    const int sr = tid >> 2, sc = tid & 3;
    const int vd = tid >> 3, vc = tid & 7;
    const size_t kbase = ((size_t)(b * NKV + kv0g + sr)) * DIMM + h * HD + 8 * sc;
    const size_t vbase = ((size_t)((b * NHEAD + h) * HD + vd)) * NKV + kv0g + 8 * vc;

    kbuf[0][sr >> 4][(sr & 15) + 16 * sc] = *(const short8*)(Kbf + kbase);
    vbuf[0][(vc >> 2) * 2 + (vd >> 4)][16 * (vc & 3) + (vd & 15)] = *(const short8*)(Vt + vbase);
    if (tid < 64) mbuf[0][tid] = -(100.f * LOG2E) * (float)mask[b * NKV + kv0g + tid];
    __syncthreads();

    f32x4 cacc0 = {0.f, 0.f, 0.f, 0.f};
    f32x4 cacc1 = {0.f, 0.f, 0.f, 0.f};
    float m_run = -1e30f, l_run = 0.f;
    int cur = 0;

    for (int t = 0; t < NTS; ++t) {
        short8 rk = {}, rv = {};
        float rm = 0.f;
        if (t < NTS - 1) {
            size_t kvn = (size_t)(t + 1) * 64;
            rk = *(const short8*)(Kbf + kbase + kvn * DIMM);
            rv = *(const short8*)(Vt + vbase + kvn);
            if (tid < 64) rm = -(100.f * LOG2E) * (float)mask[b * NKV + kv0g + kvn + tid];
        }

        f32x4 zero = {0.f, 0.f, 0.f, 0.f};
        f32x4 s[4];
        __builtin_amdgcn_s_setprio(1);
        #pragma unroll
        for (int kt = 0; kt < 4; ++kt)
            s[kt] = __builtin_amdgcn_mfma_f32_16x16x32_bf16(kbuf[cur][kt][lane], qf, zero, 0, 0, 0);
        __builtin_amdgcn_s_setprio(0);

        float ryb = ry_s[t][wq];
        #pragma unroll
        for (int kt = 0; kt < 4; ++kt) {
            #pragma unroll
            for (int r = 0; r < 4; ++r)
                s[kt][r] += rxr[kt * 4 + r] + ryb + mbuf[cur][16 * kt + 4 * g + r];
        }

        float mk[4];
        #pragma unroll
        for (int kt = 0; kt < 4; ++kt)
            mk[kt] = fmaxf(fmaxf(s[kt][0], s[kt][1]), fmaxf(s[kt][2], s[kt][3]));
        float mloc = fmaxf(fmaxf(mk[0], mk[1]), fmaxf(mk[2], mk[3]));
        mloc = fmaxf(mloc, __shfl_xor(mloc, 16));
        mloc = fmaxf(mloc, __shfl_xor(mloc, 32));

        if (!__all(mloc <= m_run + 8.f)) {
            float mnew = fmaxf(m_run, mloc);
            float fsc  = exp2f(m_run - mnew);
            l_run *= fsc;
            cacc0 *= fsc;
            cacc1 *= fsc;
            m_run = mnew;
        }

        float psum = 0.f;
        #pragma unroll
        for (int kt = 0; kt < 4; ++kt)
            #pragma unroll
            for (int r = 0; r < 4; ++r) {
                float pv = exp2f(s[kt][r] - m_run);
                s[kt][r] = pv;
                psum += pv;
            }
        psum += __shfl_xor(psum, 16);
        psum += __shfl_xor(psum, 32);
        l_run += psum;

        __builtin_amdgcn_s_setprio(1);
        #pragma unroll
        for (int sk = 0; sk < 2; ++sk) {
            #pragma unroll
            for (int kk = 0; kk < 2; ++kk) {
                int kt = sk * 2 + kk;
                unsigned d0 = cvtpk_bf16(s[kt][0], s[kt][1]);
                unsigned d1 = cvtpk_bf16(s[kt][2], s[kt][3]);
                int lt = 16 * ((2 * kt + (g >> 1)) & 3) + q15;
                uint2v* dst = (uint2v*)&pbuf[w][lt][2 * (g & 1)];
                *dst = (uint2v){d0, d1};
            }
            short8 pf = *(const short8*)&pbuf[w][lane][0];
            cacc0 = __builtin_amdgcn_mfma_f32_16x16x32_bf16(vbuf[cur][sk * 2 + 0][lane], pf, cacc0, 0, 0, 0);
            cacc1 = __builtin_amdgcn_mfma_f32_16x16x32_bf16(vbuf[cur][sk * 2 + 1][lane], pf, cacc1, 0, 0, 0);
        }
        __builtin_amdgcn_s_setprio(0);

        if (t < NTS - 1) {
            kbuf[cur ^ 1][sr >> 4][(sr & 15) + 16 * sc] = rk;
            vbuf[cur ^ 1][(vc >> 2) * 2 + (vd >> 4)][16 * (vc & 3) + (vd & 15)] = rv;
            if (tid < 64) mbuf[cur ^ 1][tid] = rm;
        }
        __syncthreads();
        cur ^= 1;
    }

    size_t prow = (size_t)(sp * NB + b) * NQP + gq;
    float* pc = pctx + prow * DIMM + h * HD;
    #pragma unroll
    for (int r = 0; r < 4; ++r) {
        pc[4 * g + r]      = cacc0[r];
        pc[16 + 4 * g + r] = cacc1[r];
    }
    if (g == 0) {
        float2 v; v.x = m_run; v.y = l_run;
        pml[prow * NHEAD + h] = v;
    }
}

// ---------------------------------------------------------------------------
// Combine the 4 KV-split partials (log2-domain m -> exp2 weights).
// ---------------------------------------------------------------------------
__global__ __launch_bounds__(256) void attn_reduce(
    const float* __restrict__ pctx, const float2* __restrict__ pml,
    float* __restrict__ CTX)
{
    const int bq = blockIdx.x;
    const int b = bq / NQ, q = bq - b * NQ;
    const int c = threadIdx.x;
    const int h = c >> 5;

    float m[SPLIT], l[SPLIT];
    #pragma unroll
    for (int sp = 0; sp < SPLIT; ++sp) {
        float2 v = pml[((size_t)(sp * NB + b) * NQP + q) * NHEAD + h];
        m[sp] = v.x; l[sp] = v.y;
    }
    float ms = fmaxf(fmaxf(m[0], m[1]), fmaxf(m[2], m[3]));
    float L = 0.f, acc = 0.f;
    #pragma unroll
    for (int sp = 0; sp < SPLIT; ++sp) {
        float wgt = exp2f(m[sp] - ms);
        L   += wgt * l[sp];
        acc += wgt * pctx[((size_t)(sp * NB + b) * NQP + q) * DIMM + c];
    }
    CTX[(size_t)bq * DIMM + c] = acc / L;
}

// ---------------------------------------------------------------------------
// fp32 GEMM for the output projection (unchanged, verified).
// ---------------------------------------------------------------------------
__global__ __launch_bounds__(256) void gemm_bias_f32(
    const float* __restrict__ A, const float* __restrict__ W,
    const float* __restrict__ bias, float* __restrict__ C,
    int M, int N, int K)
{
    __shared__ float As[32][33];
    __shared__ float Ws[32][33];
    const int t  = threadIdx.x;
    const int tr = t >> 4;
    const int tc = t & 15;
    const int brow = blockIdx.y * 32;
    const int bcol = blockIdx.x * 32;
    float acc00 = 0.f, acc01 = 0.f, acc10 = 0.f, acc11 = 0.f;

    for (int kt = 0; kt < K; kt += 32) {
        #pragma unroll
        for (int i = 0; i < 4; ++i) {
            int idx = t + i * 256;
            int r = idx >> 5, c = idx & 31;
            int gr = brow + r;
            As[r][c] = (gr < M) ? A[(size_t)gr * K + kt + c] : 0.f;
            Ws[r][c] = W[(size_t)(bcol + r) * K + kt + c];
        }
        __syncthreads();
        #pragma unroll 8
        for (int k = 0; k < 32; ++k) {
            float a0 = As[tr * 2][k], a1 = As[tr * 2 + 1][k];
            float w0 = Ws[tc * 2][k], w1 = Ws[tc * 2 + 1][k];
            acc00 += a0 * w0; acc01 += a0 * w1;
            acc10 += a1 * w0; acc11 += a1 * w1;
        }
        __syncthreads();
    }
    int gc0 = bcol + tc * 2, gc1 = gc0 + 1;
    int gr0 = brow + tr * 2, gr1 = gr0 + 1;
    if (gr0 < M) {
        C[(size_t)gr0 * N + gc0] = acc00 + bias[gc0];
        C[(size_t)gr0 * N + gc1] = acc01 + bias[gc1];
    }
    if (gr1 < M) {
        C[(size_t)gr1 * N + gc0] = acc10 + bias[gc0];
        C[(size_t)gr1 * N + gc1] = acc11 + bias[gc1];
    }
}

// ---------------------------------------------------------------------------
extern "C" void kernel_launch(void* const* d_in, const int* in_sizes, int n_in,
                              void* d_out, int out_size, void* d_ws, size_t ws_size,
                              hipStream_t stream)
{
    const float* hs   = (const float*)d_in[0];
    const float* rp   = (const float*)d_in[1];
    const float* kv   = (const float*)d_in[2];
    const int*   msk  = (const int*)d_in[4];
    const float* m1w1 = (const float*)d_in[5];
    const float* m1b1 = (const float*)d_in[6];
    const float* m1w2 = (const float*)d_in[7];
    const float* m2w1 = (const float*)d_in[8];
    const float* m2b1 = (const float*)d_in[9];
    const float* m2w2 = (const float*)d_in[10];
    const float* q_w  = (const float*)d_in[11];
    const float* q_b  = (const float*)d_in[12];
    const float* k_w  = (const float*)d_in[13];
    const float* k_b  = (const float*)d_in[14];
    const float* v_w  = (const float*)d_in[15];
    const float* v_b  = (const float*)d_in[16];
    const float* o_w  = (const float*)d_in[17];
    const float* o_b  = (const float*)d_in[18];
    float* out = (float*)d_out;

    char* p = (char*)d_ws;
    float* RX   = (float*)p; p += (size_t)NB * NQ * NHEAD * GRID * 4;
    float* RY   = (float*)p; p += (size_t)NB * NQ * NHEAD * GRID * 4;
    float* CTX  = (float*)p; p += (size_t)NB * NQ * DIMM * 4;
    u16*   Qbf  = (u16*)p;   p += (size_t)1920 * DIMM * 2;
    u16*   Kbf  = (u16*)p;   p += (size_t)NB * NKV * DIMM * 2;
    u16*   Vt   = (u16*)p;   p += (size_t)NB * NHEAD * HD * NKV * 2;

    // union region: {bf16 conv buffers} (prep..proj) / {attn partials} (attn..reduce)
    char* u = p;
    u16* hsbf = (u16*)u;
    u16* kvbf = hsbf + (size_t)1920 * DIMM;
    u16* qwbf = kvbf + (size_t)NB * NKV * DIMM;
    u16* kwbf = qwbf + (size_t)DIMM * DIMM;
    u16* vwbf = kwbf + (size_t)DIMM * DIMM;
    float*  pctx = (float*)u;
    float2* pml  = (float2*)(pctx + (size_t)SPLIT * NB * NQP * DIMM);

    const float scale = 0.17677669529663687f * LOG2E;  // 32^-0.5 * log2(e)

    // 1) fused conversion + RPE MLPs
    prep_kernel<<<CONVB + 900, 256, 0, stream>>>(
        hs, kv, q_w, k_w, v_w, rp, m1w1, m1b1, m1w2, m2w1, m2b1, m2w2,
        hsbf, kvbf, qwbf, kwbf, vwbf, RX, RY);

    // 2) Q + K + V projections in one launch (z=0 K, z=1 V, z=2 Q)
    proj_mfma<<<dim3(64, 2, 3), 256, 0, stream>>>(
        hsbf, kvbf, qwbf, q_b, kwbf, k_b, vwbf, v_b, Qbf, Kbf, Vt, scale);

    // 3) MFMA attention, KV-split x4 (verified R15/R17 kernel)
    attn_mfma<<<dim3((NQ + 63) / 64, NHEAD, NB * SPLIT), 256, 0, stream>>>(
        Qbf, Kbf, Vt, RX, RY, msk, pctx, pml);

    // 4) combine partials
    attn_reduce<<<NB * NQ, 256, 0, stream>>>(pctx, pml, CTX);

    // 5) Output projection (fp32)
    gemm_bias_f32<<<dim3(DIMM / 32, (NB * NQ + 31) / 32), 256, 0, stream>>>(
        CTX, o_w, o_b, out, NB * NQ, DIMM, DIMM);
}